// Round 5
// baseline (1039.991 us; speedup 1.0000x reference)
//
#include <hip/hip_runtime.h>
#include <stdint.h>

#define B_ROWS 32768
#define K_CENT 4096
#define D_DIM  1024
#define EPS_CAND 5e-4f

typedef unsigned short u16;
typedef __attribute__((ext_vector_type(8))) __bf16 bf16x8;
typedef __attribute__((ext_vector_type(4))) float f32x4;

__device__ inline u16 f32_to_bf16(float f) {
    unsigned u = __float_as_uint(f);
    u += 0x7FFFu + ((u >> 16) & 1u);   // round-to-nearest-even
    return (u16)(u >> 16);
}
__device__ inline float bf16_to_f32(u16 h) {
    return __uint_as_float(((unsigned)h) << 16);
}
__device__ inline unsigned ord_of_f32(float f) {
    unsigned u = __float_as_uint(f);
    return (u & 0x80000000u) ? ~u : (u | 0x80000000u);
}
__device__ inline float f32_of_ord(unsigned o) {
    unsigned u = (o & 0x80000000u) ? (o & 0x7fffffffu) : ~o;
    return __uint_as_float(u);
}
__device__ inline void gload_lds16(const u16* g, u16* l) {
    __builtin_amdgcn_global_load_lds(
        (const __attribute__((address_space(1))) void*)g,
        (__attribute__((address_space(3))) void*)l, 16, 0, 0);
}

// ---------------------------------------------------------------------------
// prep_rows: verified rounds 2-4, unchanged.
// ---------------------------------------------------------------------------
__global__ __launch_bounds__(256) void prep_rows(
    const float* __restrict__ src, u16* __restrict__ hi, u16* __restrict__ lo,
    float* __restrict__ sq, float* __restrict__ den)
{
    __shared__ double sm[4];
    const int row = blockIdx.x, tid = threadIdx.x;
    const float4 v = reinterpret_cast<const float4*>(src + (size_t)row * D_DIM)[tid];
    double ss = (double)v.x * v.x + (double)v.y * v.y
              + (double)v.z * v.z + (double)v.w * v.w;
#pragma unroll
    for (int m = 1; m < 64; m <<= 1) ss += __shfl_xor(ss, m, 64);
    if ((tid & 63) == 0) sm[tid >> 6] = ss;
    __syncthreads();
    const double tot = sm[0] + sm[1] + sm[2] + sm[3];
    const float d = fmaxf(sqrtf((float)tot), 1e-12f);
    const float n0 = v.x / d, n1 = v.y / d, n2 = v.z / d, n3 = v.w / d;

    ushort4 h, l;
    h.x = f32_to_bf16(n0); l.x = f32_to_bf16(n0 - bf16_to_f32(h.x));
    h.y = f32_to_bf16(n1); l.y = f32_to_bf16(n1 - bf16_to_f32(h.y));
    h.z = f32_to_bf16(n2); l.z = f32_to_bf16(n2 - bf16_to_f32(h.z));
    h.w = f32_to_bf16(n3); l.w = f32_to_bf16(n3 - bf16_to_f32(h.w));
    reinterpret_cast<ushort4*>(hi + (size_t)row * D_DIM)[tid] = h;
    reinterpret_cast<ushort4*>(lo + (size_t)row * D_DIM)[tid] = l;

    double s2 = (double)n0 * n0 + (double)n1 * n1
              + (double)n2 * n2 + (double)n3 * n3;
#pragma unroll
    for (int m = 1; m < 64; m <<= 1) s2 += __shfl_xor(s2, m, 64);
    __syncthreads();
    if ((tid & 63) == 0) sm[tid >> 6] = s2;
    __syncthreads();
    if (tid == 0) {
        sq[row] = (float)(sm[0] + sm[1] + sm[2] + sm[3]);
        den[row] = d;
    }
}

// ---------------------------------------------------------------------------
// gemm_cand: bf16x3 via K-augmentation (K' = 3072 = 96 k-half phases).
// One-phase-ahead pipeline: phase p = {issue 12 ds_reads for phase p+1 into
// the alternate frag set; issue 4 global_load_lds staging region r(p+3);
// 32 MFMA on this phase's frags; s_waitcnt vmcnt(4) lgkmcnt(12); s_barrier}.
// LDS = 4 rotating 32 KB regions (region = phase & 3), staged 3 phases ahead.
// ds_reads overlap the previous MFMA cluster; waits are counted, never drains.
// Safety ledger (all barriers 1/phase):
//  - R(p+1) reads region staged in phase p-2; every wave verified its own
//    slices via the trailing vmcnt(4) of phase p-1, then barrier published.
//  - staging targets r(p+3)=r(p-1); its reads R(p-1) retired before the
//    p-1 -> p barrier (trailing lgkmcnt(12) leaves only R(p)'s 12, FIFO).
//  - regions used in one phase (r(p+1) read, r(p+3) write) are distinct.
// Numeric path and epilogue identical to verified rounds 2-4.
// ---------------------------------------------------------------------------
#define BM 256
#define BN 256
#define REG_U16 16384      // one region, u16 units (32 KiB: A-half + B-half)

__global__ __launch_bounds__(512, 1) void gemm_cand(
    const u16* __restrict__ Ahi, const u16* __restrict__ Alo,
    const u16* __restrict__ Bhi, const u16* __restrict__ Blo,
    const float* __restrict__ c2, unsigned long long* __restrict__ cand)
{
    __shared__ u16 lds[4 * REG_U16];   // 128 KiB

    const int tid = threadIdx.x, lane = tid & 63, w = tid >> 6;
    const int wm = w >> 2, wn = w & 3;          // 2M x 4N wave grid
    const int fr = lane & 15, fc = lane >> 4;

    // bijective XCD swizzle (2048 = 8 x 256) + serpentine colblock
    const int flat = blockIdx.x;
    const int swz = (flat & 7) * 256 + (flat >> 3);
    int bx = swz & 15;                 // colblock 0..15
    const int by = swz >> 4;           // rowblock 0..127
    if (by & 1) bx = 15 - bx;
    const size_t arow0 = (size_t)by * BM;
    const size_t brow0 = (size_t)bx * BN;

    // staging lane offsets (involution on GLOBAL src; LDS dest linear)
    const int prow = tid >> 2, pch = tid & 3;
    const int lc = pch ^ ((prow >> 1) & 3);
    const size_t lane0 = (size_t)prow * D_DIM + lc * 8;
    const size_t lane1 = (size_t)(prow + 128) * D_DIM + lc * 8;
    const int dst0 = tid * 8, dst1 = tid * 8 + 4096;   // u16 within half
    const size_t abase = arow0 * D_DIM;
    const size_t bbase = brow0 * D_DIM;

    // stage K-tile tn, k-half jj -> region (2*tn+jj)&3 (4 gloads/wave)
#define STAGE_R(tn, jj) do {                                                  \
    u16* _d = lds + ((2 * (tn) + (jj)) & 3) * REG_U16;                        \
    const size_t _k = (size_t)(((tn) & 15) * 64 + (jj) * 32);                 \
    const u16* _sa = ((((tn) >> 4) == 1) ? Alo : Ahi) + abase + _k;           \
    const u16* _sb = ((((tn) >> 4) == 2) ? Blo : Bhi) + bbase + _k;           \
    gload_lds16(_sa + lane0, _d + dst0);                                      \
    gload_lds16(_sa + lane1, _d + dst1);                                      \
    gload_lds16(_sb + lane0, _d + 8192 + dst0);                               \
    gload_lds16(_sb + lane1, _d + 8192 + dst1);                               \
} while (0)

    // fragment ds_read offsets (u16, region-half-relative, phase-invariant)
    int offA[8], offB[4];
#pragma unroll
    for (int i = 0; i < 8; ++i) {
        const int r = wm * 128 + i * 16 + fr;
        offA[i] = r * 32 + ((fc ^ ((r >> 1) & 3)) * 8);
    }
#pragma unroll
    for (int n = 0; n < 4; ++n) {
        const int r = wn * 64 + n * 16 + fr;
        offB[n] = r * 32 + ((fc ^ ((r >> 1) & 3)) * 8);
    }

    f32x4 acc[8][4] = {};
    bf16x8 afE[8], bfE[4], afO[8], bfO[4];

    // phase p: read R(p+1) from region RR=(p+1)&3 into AFR/BFR; stage
    // (TST,JST) if DOSTAGE; MFMA on AFU/BFU; trailing counted waits; barrier.
#define PHASE(RR, AFU, BFU, AFR, BFR, TST, JST, DOSTAGE, TRAILVM) do {        \
    const u16* _r = lds + (RR) * REG_U16;                                     \
    _Pragma("unroll")                                                         \
    for (int _i = 0; _i < 8; ++_i)                                            \
        AFR[_i] = *reinterpret_cast<const bf16x8*>(_r + offA[_i]);            \
    _Pragma("unroll")                                                         \
    for (int _n = 0; _n < 4; ++_n)                                            \
        BFR[_n] = *reinterpret_cast<const bf16x8*>(_r + 8192 + offB[_n]);     \
    __builtin_amdgcn_sched_barrier(0);                                        \
    if (DOSTAGE) STAGE_R(TST, JST);                                           \
    __builtin_amdgcn_sched_barrier(0);                                        \
    __builtin_amdgcn_s_setprio(1);                                            \
    _Pragma("unroll")                                                         \
    for (int _i = 0; _i < 8; ++_i)                                            \
        _Pragma("unroll")                                                     \
        for (int _n = 0; _n < 4; ++_n)                                        \
            acc[_i][_n] = __builtin_amdgcn_mfma_f32_16x16x32_bf16(            \
                AFU[_i], BFU[_n], acc[_i][_n], 0, 0, 0);                      \
    __builtin_amdgcn_s_setprio(0);                                            \
    __builtin_amdgcn_sched_barrier(0);                                        \
    asm volatile("s_waitcnt vmcnt(" TRAILVM ") lgkmcnt(12)" ::: "memory");    \
    __builtin_amdgcn_sched_barrier(0);                                        \
    __builtin_amdgcn_s_barrier();                                             \
} while (0)

    // prologue: stage regions 0,1,2 (tiles 0.kh0, 0.kh1, 1.kh0); verify own
    // r0+r1 slices (12 outstanding -> 4); barrier; read R(0) into E.
    STAGE_R(0, 0); STAGE_R(0, 1); STAGE_R(1, 0);
    asm volatile("s_waitcnt vmcnt(4)" ::: "memory");
    __builtin_amdgcn_sched_barrier(0);
    __builtin_amdgcn_s_barrier();
    {
        const u16* _r = lds;   // region 0
#pragma unroll
        for (int i = 0; i < 8; ++i)
            afE[i] = *reinterpret_cast<const bf16x8*>(_r + offA[i]);
#pragma unroll
        for (int n = 0; n < 4; ++n)
            bfE[n] = *reinterpret_cast<const bf16x8*>(_r + 8192 + offB[n]);
    }
    __builtin_amdgcn_sched_barrier(0);

    // main loop: phases 0..91 (tiles 0..45 fully uniform)
    for (int s = 0; s < 23; ++s) {
        const int t2 = 2 * s;
        PHASE(1, afE, bfE, afO, bfO, t2 + 1, 1, true, "4");   // p=4s+0
        PHASE(2, afO, bfO, afE, bfE, t2 + 2, 0, true, "4");   // p=4s+1
        PHASE(3, afE, bfE, afO, bfO, t2 + 2, 1, true, "4");   // p=4s+2
        PHASE(0, afO, bfO, afE, bfE, t2 + 3, 0, true, "4");   // p=4s+3
    }
    // tail: phases 92..95 (tiles 46,47)
    PHASE(1, afE, bfE, afO, bfO, 47, 1, true,  "4");          // p=92
    PHASE(2, afO, bfO, afE, bfE, 0,  0, false, "0");          // p=93
    {   // p=94: read R(95) from region 3 -> O; MFMA E (no stage/waits needed)
        const u16* _r = lds + 3 * REG_U16;
#pragma unroll
        for (int i = 0; i < 8; ++i)
            afO[i] = *reinterpret_cast<const bf16x8*>(_r + offA[i]);
#pragma unroll
        for (int n = 0; n < 4; ++n)
            bfO[n] = *reinterpret_cast<const bf16x8*>(_r + 8192 + offB[n]);
        __builtin_amdgcn_s_setprio(1);
#pragma unroll
        for (int i = 0; i < 8; ++i)
#pragma unroll
            for (int n = 0; n < 4; ++n)
                acc[i][n] = __builtin_amdgcn_mfma_f32_16x16x32_bf16(
                    afE[i], bfE[n], acc[i][n], 0, 0, 0);
        __builtin_amdgcn_s_setprio(0);
    }
    {   // p=95: MFMA O
        __builtin_amdgcn_s_setprio(1);
#pragma unroll
        for (int i = 0; i < 8; ++i)
#pragma unroll
            for (int n = 0; n < 4; ++n)
                acc[i][n] = __builtin_amdgcn_mfma_f32_16x16x32_bf16(
                    afO[i], bfO[n], acc[i][n], 0, 0, 0);
        __builtin_amdgcn_s_setprio(0);
    }
#undef PHASE
#undef STAGE_R

    // epilogue: per-row min over this wave's 64 columns -> cand[row][group]
    const int group = bx * 4 + wn;
    float c2v[4];
#pragma unroll
    for (int n = 0; n < 4; ++n)
        c2v[n] = c2[brow0 + wn * 64 + n * 16 + fr];

#pragma unroll
    for (int mi = 0; mi < 8; ++mi) {
#pragma unroll
        for (int r = 0; r < 4; ++r) {
            unsigned long long bk = ~0ull;
#pragma unroll
            for (int ni = 0; ni < 4; ++ni) {
                const float d2a = c2v[ni] - 2.0f * acc[mi][ni][r];
                const unsigned col = (unsigned)(brow0 + wn * 64 + ni * 16 + fr);
                const unsigned long long key =
                    ((unsigned long long)ord_of_f32(d2a) << 32) | col;
                if (key < bk) bk = key;
            }
#pragma unroll
            for (int ms = 1; ms < 16; ms <<= 1) {
                const unsigned long long o = __shfl_xor(bk, ms, 64);
                if (o < bk) bk = o;
            }
            if (fr == 0) {
                const size_t grow = arow0 + wm * 128 + mi * 16 + fc * 4 + r;
                cand[grow * 64 + group] = bk;
            }
        }
    }
}

// ---------------------------------------------------------------------------
// finalize: verified rounds 2-4, unchanged.
// ---------------------------------------------------------------------------
__global__ __launch_bounds__(256) void finalize(
    const unsigned long long* __restrict__ cand,
    const float* __restrict__ X, const float* __restrict__ C,
    const float* __restrict__ denx, const float* __restrict__ denc,
    const float* __restrict__ x2, const float* __restrict__ c2,
    float* __restrict__ out)
{
    const int w = threadIdx.x >> 6, lane = threadIdx.x & 63;
    const size_t row = (size_t)blockIdx.x * 4 + w;

    const unsigned long long v = cand[row * 64 + lane];
    unsigned long long m = v;
#pragma unroll
    for (int ms = 1; ms < 64; ms <<= 1) {
        const unsigned long long o = __shfl_xor(m, ms, 64);
        if (o < m) m = o;
    }
    const float fmin = f32_of_ord((unsigned)(m >> 32));
    const bool is_cand = f32_of_ord((unsigned)(v >> 32)) <= fmin + EPS_CAND;
    const unsigned long long ball = __ballot(is_cand);

    unsigned win;
    if (__popcll(ball) == 1) {
        win = (unsigned)(m & 0xffffffffu);
    } else {
        const float dxr = denx[row];
        const float x2r = x2[row];
        float xv[16];
#pragma unroll
        for (int j = 0; j < 16; ++j)
            xv[j] = X[row * D_DIM + j * 64 + lane] / dxr;

        float bestd2 = __uint_as_float(0x7f800000u);
        unsigned bwin = 0xffffffffu;
        unsigned long long bb = ball;
        while (bb) {
            const int l = __ffsll((unsigned long long)bb) - 1;
            bb &= bb - 1;
            const unsigned col = (unsigned)(__shfl(v, l, 64) & 0xffffffffu);
            const float dcr = denc[col];
            double s = 0.0;
#pragma unroll
            for (int j = 0; j < 16; ++j) {
                const float cv = C[(size_t)col * D_DIM + j * 64 + lane] / dcr;
                s = fma((double)xv[j], (double)cv, s);
            }
#pragma unroll
            for (int ms = 1; ms < 64; ms <<= 1) s += __shfl_xor(s, ms, 64);
            const float dotf = (float)s;
            const float d2 = (x2r + c2[col]) - 2.0f * dotf;
            if (d2 < bestd2 || (d2 == bestd2 && col < bwin)) {
                bestd2 = d2; bwin = col;
            }
        }
        win = bwin;
    }

    const float4* s4 = reinterpret_cast<const float4*>(C + (size_t)win * D_DIM);
    float4* d4 = reinterpret_cast<float4*>(out + row * D_DIM);
#pragma unroll
    for (int t = 0; t < 4; ++t) d4[t * 64 + lane] = s4[t * 64 + lane];
}

extern "C" void kernel_launch(void* const* d_in, const int* in_sizes, int n_in,
                              void* d_out, int out_size, void* d_ws, size_t ws_size,
                              hipStream_t stream)
{
    (void)in_sizes; (void)n_in; (void)out_size; (void)ws_size;
    const float* X = (const float*)d_in[0];   // [32768,1024] f32
    const float* C = (const float*)d_in[1];   // [4096,1024]  f32
    float* out = (float*)d_out;               // [32768,1024] f32

    char* ws = (char*)d_ws;
    u16* Ahi = (u16*)ws;                                     // 64 MiB
    u16* Alo = Ahi + (size_t)B_ROWS * D_DIM;                 // 64 MiB
    u16* Bhi = Alo + (size_t)B_ROWS * D_DIM;                 //  8 MiB
    u16* Blo = Bhi + (size_t)K_CENT * D_DIM;                 //  8 MiB
    unsigned long long* cand =
        (unsigned long long*)(Blo + (size_t)K_CENT * D_DIM); // 16 MiB
    float* c2   = (float*)(cand + (size_t)B_ROWS * 64);      // 16 KiB
    float* x2   = c2 + K_CENT;                               // 128 KiB
    float* denx = x2 + B_ROWS;                               // 128 KiB
    float* denc = denx + B_ROWS;                             // 16 KiB

    prep_rows<<<B_ROWS, 256, 0, stream>>>(X, Ahi, Alo, x2, denx);
    prep_rows<<<K_CENT, 256, 0, stream>>>(C, Bhi, Blo, c2, denc);
    gemm_cand<<<(B_ROWS / BM) * (K_CENT / BN), 512, 0, stream>>>(
        Ahi, Alo, Bhi, Blo, c2, cand);
    finalize<<<B_ROWS / 4, 256, 0, stream>>>(
        cand, X, C, denx, denc, x2, c2, out);
}